// Round 10
// baseline (2549.370 us; speedup 1.0000x reference)
//
#include <hip/hip_runtime.h>
#include <stdint.h>

// QuantizedLinear: out[N,OUT_F] = requant(int8gemm(x, W^T) + bias)
// x: [8192,4096] int8 (pushed int32), W: [4096,4096] int8 (pushed int32)
// out: int8 values stored as int32 (harness reads d_out as np.int32)
//
// r10: TLP instead of ILP. 2-slot double buffer (64 KiB LDS) -> 2 blocks/CU,
// __launch_bounds__(512,4) caps VGPR at 128 (4 waves/SIMD). The two resident
// blocks are not barrier-synced, so one block's LDS read burst overlaps the
// other's MFMA burst (m114 co-scheduling). Simple same-tile read->MFMA body,
// one barrier per tile (at end), vmcnt(0) drained during MFMA burst.
// Fragment-ordered panels (0 bank conflicts), mfma_i32_32x32x32_i8,
// setprio, XCD-bijective swizzle.

#define M_DIM 8192
#define N_DIM 4096
#define K_DIM 4096
#define BM 256
#define BN 256
#define NKT2 (K_DIM / 32)            // 128 k-subtiles in panel layout
#define NT (K_DIM / 64)              // 64 K-tiles (2 subtiles each)
#define NBLK ((M_DIM / BM) * (N_DIM / BN))   // 512 = 2 per CU
#define ABUF (BM * 64)               // 16 KiB per slot
#define BBUF (BN * 64)               // 16 KiB per slot

using i32x4  = __attribute__((ext_vector_type(4))) int;
using i32x16 = __attribute__((ext_vector_type(16))) int;

typedef const __attribute__((address_space(1))) uint32_t* gptr_t;
typedef __attribute__((address_space(3))) uint32_t* lptr_t;

__device__ __forceinline__ void gload_lds16(const void* g, void* l) {
    __builtin_amdgcn_global_load_lds((gptr_t)g, (lptr_t)l, 16, 0, 0);
}

__device__ __forceinline__ int pack4(i32x4 v) {
    return (int)(((unsigned)v.x & 0xFFu) | (((unsigned)v.y & 0xFFu) << 8) |
                 (((unsigned)v.z & 0xFFu) << 16) | (((unsigned)v.w) << 24));
}

// int32 [rows][K_DIM] -> fragment-ordered panels [rows/32][NKT2][1024]
// block (rb,kt): byte[l*16+j] = (int8)src[rb*32 + (l&31)][kt*32 + (l>>5)*16 + j]
__global__ void pack_panels32_kernel(const int* __restrict__ src, int8_t* __restrict__ dst,
                                     int n_blocks) {
    int gid = blockIdx.x * blockDim.x + threadIdx.x;
    int blk = gid >> 6;
    int l = gid & 63;
    if (blk >= n_blocks) return;
    int rb = blk >> 7;               // / NKT2
    int kt = blk & (NKT2 - 1);
    const i32x4* s4 = (const i32x4*)(src + (size_t)(rb * 32 + (l & 31)) * K_DIM
                                         + kt * 32 + (l >> 5) * 16);
    i32x4 o;
    o.x = pack4(s4[0]); o.y = pack4(s4[1]); o.z = pack4(s4[2]); o.w = pack4(s4[3]);
    *(i32x4*)(dst + (size_t)blk * 1024 + l * 16) = o;
}

#define MFMA32(a, b, c) __builtin_amdgcn_mfma_i32_32x32x32_i8((a), (b), (c), 0, 0, 0)

// Lane-linear fragment reads; bases include wave offset + lane*16.
// All slot/r/c/k offsets fold into ds_read offset immediates (< 64K).
#define RA(S, R, K) (*(const i32x4*)(Ard + (S) * ABUF + (R) * 2048 + (K) * 1024))
#define RB(S, C, K) (*(const i32x4*)(Brd + (S) * BBUF + (C) * 2048 + (K) * 1024))

// Stage next tile into slot (4 gload_lds/wave), advance running pointers.
#define STAGE(SLOT)                                                     \
    gload_lds16(AgS,        ldsA + (SLOT) * ABUF + waoff);              \
    gload_lds16(AgS + 1024, ldsA + (SLOT) * ABUF + waoff + 1024);       \
    gload_lds16(BgS,        ldsB + (SLOT) * BBUF + waoff);              \
    gload_lds16(BgS + 1024, ldsB + (SLOT) * BBUF + waoff + 1024);       \
    AgS += 2048; BgS += 2048;

// One K-tile on slot S: 12 ds_reads, optional stage of next tile into S^1,
// 16 MFMA (compiler interleaves fine-grained lgkm waits), then sync.
#define TILE(S, STAGE_STMTS, SYNC_STMTS)                                          \
  { i32x4 a00 = RA(S,0,0), a10 = RA(S,1,0), a20 = RA(S,2,0), a30 = RA(S,3,0);     \
    i32x4 b00 = RB(S,0,0), b10 = RB(S,1,0);                                       \
    i32x4 a01 = RA(S,0,1), a11 = RA(S,1,1), a21 = RA(S,2,1), a31 = RA(S,3,1);     \
    i32x4 b01 = RB(S,0,1), b11 = RB(S,1,1);                                       \
    STAGE_STMTS;                                                                  \
    __builtin_amdgcn_s_setprio(1);                                                \
    acc[0][0] = MFMA32(a00, b00, acc[0][0]); acc[0][1] = MFMA32(a00, b10, acc[0][1]); \
    acc[1][0] = MFMA32(a10, b00, acc[1][0]); acc[1][1] = MFMA32(a10, b10, acc[1][1]); \
    acc[2][0] = MFMA32(a20, b00, acc[2][0]); acc[2][1] = MFMA32(a20, b10, acc[2][1]); \
    acc[3][0] = MFMA32(a30, b00, acc[3][0]); acc[3][1] = MFMA32(a30, b10, acc[3][1]); \
    acc[0][0] = MFMA32(a01, b01, acc[0][0]); acc[0][1] = MFMA32(a01, b11, acc[0][1]); \
    acc[1][0] = MFMA32(a11, b01, acc[1][0]); acc[1][1] = MFMA32(a11, b11, acc[1][1]); \
    acc[2][0] = MFMA32(a21, b01, acc[2][0]); acc[2][1] = MFMA32(a21, b11, acc[2][1]); \
    acc[3][0] = MFMA32(a31, b01, acc[3][0]); acc[3][1] = MFMA32(a31, b11, acc[3][1]); \
    __builtin_amdgcn_s_setprio(0);                                                \
    SYNC_STMTS; }

#define SYNC_FULL                                                       \
    asm volatile("s_waitcnt vmcnt(0)" ::: "memory");                    \
    __builtin_amdgcn_s_barrier();

__global__ __launch_bounds__(512, 4)
void qgemm32_kernel(const int8_t* __restrict__ xp, const int8_t* __restrict__ wp,
                    const int* __restrict__ bias, const float* __restrict__ wscale,
                    const float* __restrict__ iscale, const float* __restrict__ oscale,
                    const int* __restrict__ zp, int* __restrict__ out) {
    __shared__ int8_t lds[2 * (ABUF + BBUF)];   // 64 KiB -> 2 blocks/CU
    int8_t* ldsA = lds;               // 2 slots * 16 KiB, [rsub 0..7][ksub 0..1][1024]
    int8_t* ldsB = lds + 2 * ABUF;    // 2 slots * 16 KiB, [csub 0..7][ksub 0..1][1024]

    const int tid  = threadIdx.x;
    const int wave = tid >> 6;
    const int lane = tid & 63;

    // XCD-bijective swizzle (NBLK = 512, divisible by 8)
    int b = blockIdx.x;
    int s = (b & 7) * (NBLK >> 3) + (b >> 3);
    const int bcol = (s & 15) * BN;   // N_DIM/BN = 16
    const int brow = (s >> 4) * BM;

    const int wr = wave >> 2;         // 0..1  (M half, 128 rows = 4 rsubs)
    const int wc = wave & 3;          // 0..3  (N quarter, 64 cols = 2 csubs)

    // staging sources (fragment-ordered panels; advance 2048 B per K-tile)
    const int rb0 = brow >> 5;
    const int cb0 = bcol >> 5;
    const int8_t* AgS = xp + ((size_t)(rb0 + wave) * NKT2) * 1024 + lane * 16;
    const int8_t* BgS = wp + ((size_t)(cb0 + wave) * NKT2) * 1024 + lane * 16;
    const int waoff = wave * 2048;

    // fragment read bases (all else folds into ds_read offset immediates)
    const int8_t* Ard = ldsA + wr * 8192 + lane * 16;
    const int8_t* Brd = ldsB + wc * 4096 + lane * 16;

    i32x16 acc[4][2] = {};

    // ---- prologue: stage tile0 -> slot0; land it ----
    STAGE(0)
    SYNC_FULL

    // ---- main loop: 31 pairs, t = 0..61, staging t+1 into the other slot ----
    for (int i = 0; i < 31; ++i) {
        TILE(0, STAGE(1), SYNC_FULL)
        TILE(1, STAGE(0), SYNC_FULL)
    }
    // ---- t=62 (slot0): stage tile63 -> slot1 ----
    TILE(0, STAGE(1), SYNC_FULL)
    // ---- t=63 (slot1): final compute, no stage/sync ----
    TILE(1, ((void)0), ((void)0))

    // ---- epilogue: out = clip(round((acc + bias) * (is*ws/os) + zp)) as int32 ----
    // 32x32 C/D layout (HW-verified): col = lane&31, row = (reg&3) + 8*(reg>>2) + 4*(lane>>5)
    const float is_v = iscale[0];
    const float os_v = oscale[0];
    const float zpf = (float)zp[0];
    #pragma unroll
    for (int c = 0; c < 2; c++) {
        int col = bcol + wc * 64 + c * 32 + (lane & 31);
        float sf = (is_v * wscale[col]) / os_v;
        int bz = bias[col];
        #pragma unroll
        for (int r = 0; r < 4; r++) {
            int rowb = brow + wr * 128 + r * 32 + 4 * (lane >> 5);
            #pragma unroll
            for (int reg = 0; reg < 16; reg++) {
                int row = rowb + (reg & 3) + 8 * (reg >> 2);
                float v = (float)(acc[r][c][reg] + bz) * sf + zpf;
                v = rintf(v);
                v = fminf(fmaxf(v, -128.0f), 127.0f);
                out[(size_t)row * N_DIM + col] = (int)v;
            }
        }
    }
}

#define MFMA_I8(a, b, c) __builtin_amdgcn_mfma_i32_16x16x64_i8((a), (b), (c), 0, 0, 0)

// Fallback (no workspace): direct int32 consumption, 128^2 tile (round-2 proven).
__global__ void qgemm_fallback(const int* __restrict__ x32, const int* __restrict__ w32,
                               const int* __restrict__ bias, const float* __restrict__ wscale,
                               const float* __restrict__ iscale, const float* __restrict__ oscale,
                               const int* __restrict__ zp, int* __restrict__ out) {
    __shared__ int8_t As[128][64];
    __shared__ int8_t Bs[128][64];
    const int tid  = threadIdx.x;
    const int wave = tid >> 6;
    const int lane = tid & 63;
    int b = blockIdx.x;
    int s = (b & 7) * (gridDim.x >> 3) + (b >> 3);
    const int bcol = (s & 31) * 128;
    const int brow = (s >> 5) * 128;
    const int wr = wave >> 1;
    const int wc = wave & 1;
    i32x4 acc[4][4] = {};
    for (int kt = 0; kt < K_DIM; kt += 64) {
        int row = tid >> 1;
        int h = tid & 1;
        const i32x4* sa = (const i32x4*)(x32 + (size_t)(brow + row) * K_DIM + kt + h * 32);
        const i32x4* sb = (const i32x4*)(w32 + (size_t)(bcol + row) * K_DIM + kt + h * 32);
        int pa[8], pb[8];
        #pragma unroll
        for (int j = 0; j < 8; j++) { pa[j] = pack4(sa[j]); pb[j] = pack4(sb[j]); }
        *(i32x4*)&As[row][h * 32]      = *(i32x4*)&pa[0];
        *(i32x4*)&As[row][h * 32 + 16] = *(i32x4*)&pa[4];
        *(i32x4*)&Bs[row][h * 32]      = *(i32x4*)&pb[0];
        *(i32x4*)&Bs[row][h * 32 + 16] = *(i32x4*)&pb[4];
        __syncthreads();
        i32x4 a_frag[4], b_frag[4];
        #pragma unroll
        for (int m = 0; m < 4; m++)
            a_frag[m] = *(const i32x4*)&As[wr * 64 + m * 16 + (lane & 15)][(lane >> 4) * 16];
        #pragma unroll
        for (int n = 0; n < 4; n++)
            b_frag[n] = *(const i32x4*)&Bs[wc * 64 + n * 16 + (lane & 15)][(lane >> 4) * 16];
        #pragma unroll
        for (int m = 0; m < 4; m++)
            #pragma unroll
            for (int n = 0; n < 4; n++)
                acc[m][n] = MFMA_I8(a_frag[m], b_frag[n], acc[m][n]);
        __syncthreads();
    }
    const float is_v = iscale[0];
    const float os_v = oscale[0];
    const float zpf = (float)zp[0];
    #pragma unroll
    for (int n = 0; n < 4; n++) {
        int col = bcol + wc * 64 + n * 16 + (lane & 15);
        float sf = (is_v * wscale[col]) / os_v;
        int bz = bias[col];
        #pragma unroll
        for (int m = 0; m < 4; m++) {
            int row0 = brow + wr * 64 + m * 16 + (lane >> 4) * 4;
            #pragma unroll
            for (int r = 0; r < 4; r++) {
                float v = (float)(acc[m][n][r] + bz) * sf + zpf;
                v = rintf(v);
                v = fminf(fmaxf(v, -128.0f), 127.0f);
                out[(size_t)(row0 + r) * N_DIM + col] = (int)v;
            }
        }
    }
}

extern "C" void kernel_launch(void* const* d_in, const int* in_sizes, int n_in,
                              void* d_out, int out_size, void* d_ws, size_t ws_size,
                              hipStream_t stream) {
    const int*   x32    = (const int*)d_in[0];
    const int*   w32    = (const int*)d_in[1];
    const int*   bias   = (const int*)d_in[2];
    const float* wscale = (const float*)d_in[3];
    const float* iscale = (const float*)d_in[4];
    const float* oscale = (const float*)d_in[5];
    const int*   zp     = (const int*)d_in[6];
    int* out = (int*)d_out;

    const size_t need = (size_t)M_DIM * K_DIM + (size_t)N_DIM * K_DIM;  // 50.3 MB

    if (ws_size >= need) {
        int8_t* xp = (int8_t*)d_ws;
        int8_t* wp = xp + (size_t)M_DIM * K_DIM;
        const int nblkA = (M_DIM / 32) * NKT2;   // 32768
        const int nblkB = (N_DIM / 32) * NKT2;   // 16384
        pack_panels32_kernel<<<nblkA / 4, 256, 0, stream>>>(x32, xp, nblkA);
        pack_panels32_kernel<<<nblkB / 4, 256, 0, stream>>>(w32, wp, nblkB);
        qgemm32_kernel<<<NBLK, 512, 0, stream>>>(xp, wp, bias, wscale, iscale, oscale, zp, out);
    } else {
        qgemm_fallback<<<2048, 256, 0, stream>>>(x32, w32, bias, wscale, iscale, oscale, zp, out);
    }
}

// Round 12
// 183.260 us; speedup vs baseline: 13.9112x; 13.9112x over previous
//
#include <hip/hip_runtime.h>
#include <stdint.h>

// QuantizedLinear: out[N,OUT_F] = requant(int8gemm(x, W^T) + bias)
// x: [8192,4096] int8 (pushed int32), W: [4096,4096] int8 (pushed int32)
// out: int8 values stored as int32 (harness reads d_out as np.int32)
//
// r12: r11's asm-read pipeline with the RACE FIXED. Order per tile t:
//   STAGE(t+2) -> vmcnt(4)  [t+1's staging landed; only t+2's 4 in flight]
//   -> s_barrier             [all waves agree slot t+1 is ready]
//   -> READ12(slot t+1) asm  [no compiler waits]
//   -> lgkmcnt(12)           [prev tile's 12 reads done; these 12 outstanding]
//   -> sched_barrier -> 16 MFMA on last tile's regs (reads drain underneath).
// 4-slot LDS ring, fragment-ordered panels (0 conflicts), 32x32x32 i8 MFMA,
// counted vmcnt/lgkmcnt (never 0 until tail), setprio, XCD swizzle.

#define M_DIM 8192
#define N_DIM 4096
#define K_DIM 4096
#define BM 256
#define BN 256
#define NKT2 (K_DIM / 32)            // 128 k-subtiles in panel layout
#define NBLK ((M_DIM / BM) * (N_DIM / BN))   // 512
#define ABUF (BM * 64)               // 16 KiB per slot
#define BBUF (BN * 64)               // 16 KiB per slot

using i32x4  = __attribute__((ext_vector_type(4))) int;
using i32x16 = __attribute__((ext_vector_type(16))) int;

typedef const __attribute__((address_space(1))) uint32_t* gptr_t;
typedef __attribute__((address_space(3))) uint32_t* lptr_t;

__device__ __forceinline__ void gload_lds16(const void* g, void* l) {
    __builtin_amdgcn_global_load_lds((gptr_t)g, (lptr_t)l, 16, 0, 0);
}

__device__ __forceinline__ int pack4(i32x4 v) {
    return (int)(((unsigned)v.x & 0xFFu) | (((unsigned)v.y & 0xFFu) << 8) |
                 (((unsigned)v.z & 0xFFu) << 16) | (((unsigned)v.w) << 24));
}

// int32 [rows][K_DIM] -> fragment-ordered panels [rows/32][NKT2][1024]
// block (rb,kt): byte[l*16+j] = (int8)src[rb*32 + (l&31)][kt*32 + (l>>5)*16 + j]
__global__ void pack_panels32_kernel(const int* __restrict__ src, int8_t* __restrict__ dst,
                                     int n_blocks) {
    int gid = blockIdx.x * blockDim.x + threadIdx.x;
    int blk = gid >> 6;
    int l = gid & 63;
    if (blk >= n_blocks) return;
    int rb = blk >> 7;               // / NKT2
    int kt = blk & (NKT2 - 1);
    const i32x4* s4 = (const i32x4*)(src + (size_t)(rb * 32 + (l & 31)) * K_DIM
                                         + kt * 32 + (l >> 5) * 16);
    i32x4 o;
    o.x = pack4(s4[0]); o.y = pack4(s4[1]); o.z = pack4(s4[2]); o.w = pack4(s4[3]);
    *(i32x4*)(dst + (size_t)blk * 1024 + l * 16) = o;
}

#define MFMA32(a, b, c) __builtin_amdgcn_mfma_i32_32x32x32_i8((a), (b), (c), 0, 0, 0)

// Inline-asm LDS read: compiler inserts NO automatic lgkm waits for these.
#define DSR(dst, base, off) \
    asm volatile("ds_read_b128 %0, %1 offset:%2" : "=&v"(dst) : "v"(base), "i"(off))

// Issue all 12 prefetch reads for the k-tile in LDS slot at byte SOFF.
#define READ12(NS, SOFF)                                                        \
    DSR(fA[NS][0][0], aA, (SOFF) + 0);    DSR(fA[NS][0][1], aA, (SOFF) + 2048); \
    DSR(fA[NS][0][2], aA, (SOFF) + 4096); DSR(fA[NS][0][3], aA, (SOFF) + 6144); \
    DSR(fA[NS][1][0], aA, (SOFF) + 1024); DSR(fA[NS][1][1], aA, (SOFF) + 3072); \
    DSR(fA[NS][1][2], aA, (SOFF) + 5120); DSR(fA[NS][1][3], aA, (SOFF) + 7168); \
    DSR(fB[NS][0][0], aB, (SOFF) + 0);    DSR(fB[NS][0][1], aB, (SOFF) + 2048); \
    DSR(fB[NS][1][0], aB, (SOFF) + 1024); DSR(fB[NS][1][1], aB, (SOFF) + 3072);

// 8 independent MFMAs on set CS, k-half K.
#define MFMA_HALF(CS, K)                                                          \
    acc[0][0] = MFMA32(fA[CS][K][0], fB[CS][K][0], acc[0][0]);                    \
    acc[0][1] = MFMA32(fA[CS][K][0], fB[CS][K][1], acc[0][1]);                    \
    acc[1][0] = MFMA32(fA[CS][K][1], fB[CS][K][0], acc[1][0]);                    \
    acc[1][1] = MFMA32(fA[CS][K][1], fB[CS][K][1], acc[1][1]);                    \
    acc[2][0] = MFMA32(fA[CS][K][2], fB[CS][K][0], acc[2][0]);                    \
    acc[2][1] = MFMA32(fA[CS][K][2], fB[CS][K][1], acc[2][1]);                    \
    acc[3][0] = MFMA32(fA[CS][K][3], fB[CS][K][0], acc[3][0]);                    \
    acc[3][1] = MFMA32(fA[CS][K][3], fB[CS][K][1], acc[3][1]);

// Stage next tile into slot (4 gload_lds/wave), advance running pointers.
#define STAGE(SLOT)                                                     \
    gload_lds16(AgS,        ldsA + (SLOT) * ABUF + waoff);              \
    gload_lds16(AgS + 1024, ldsA + (SLOT) * ABUF + waoff + 1024);       \
    gload_lds16(BgS,        ldsB + (SLOT) * BBUF + waoff);              \
    gload_lds16(BgS + 1024, ldsB + (SLOT) * BBUF + waoff + 1024);       \
    AgS += 2048; BgS += 2048;

// Steady-state tile t: stage t+2, land t+1 (vmcnt(4)+barrier), asm-read t+1,
// wait prev tile's reads only (lgkmcnt(12)), MFMA tile t.
#define TILE_FULL(SLOT_STG, SOFF_NXT, NS, CS)                           \
  { STAGE(SLOT_STG)                                                     \
    asm volatile("s_waitcnt vmcnt(4)" ::: "memory");                    \
    __builtin_amdgcn_s_barrier();                                       \
    READ12(NS, SOFF_NXT)                                                \
    asm volatile("s_waitcnt lgkmcnt(12)" ::: "memory");                 \
    __builtin_amdgcn_sched_barrier(0);                                  \
    __builtin_amdgcn_s_setprio(1);                                      \
    MFMA_HALF(CS, 0)                                                    \
    MFMA_HALF(CS, 1)                                                    \
    __builtin_amdgcn_s_setprio(0); }

__global__ __launch_bounds__(512, 2)
void qgemm32_kernel(const int8_t* __restrict__ xp, const int8_t* __restrict__ wp,
                    const int* __restrict__ bias, const float* __restrict__ wscale,
                    const float* __restrict__ iscale, const float* __restrict__ oscale,
                    const int* __restrict__ zp, int* __restrict__ out) {
    extern __shared__ int8_t lds[];
    int8_t* ldsA = lds;               // 4 slots * 16 KiB
    int8_t* ldsB = lds + 4 * ABUF;    // 4 slots * 16 KiB

    const int tid  = threadIdx.x;
    const int wave = tid >> 6;
    const int lane = tid & 63;

    // XCD-bijective swizzle (NBLK = 512, divisible by 8)
    int b = blockIdx.x;
    int s = (b & 7) * (NBLK >> 3) + (b >> 3);
    const int bcol = (s & 15) * BN;   // N_DIM/BN = 16
    const int brow = (s >> 4) * BM;

    const int wr = wave >> 2;         // 0..1  (M half, 128 rows = 4 rsubs)
    const int wc = wave & 3;          // 0..3  (N quarter, 64 cols = 2 csubs)

    // staging sources (fragment-ordered panels; advance 2048 B per K-tile)
    const int rb0 = brow >> 5;
    const int cb0 = bcol >> 5;
    const int8_t* AgS = xp + ((size_t)(rb0 + wave) * NKT2) * 1024 + lane * 16;
    const int8_t* BgS = wp + ((size_t)(cb0 + wave) * NKT2) * 1024 + lane * 16;
    const int waoff = wave * 2048;

    // asm ds_read base addresses (low 32 bits of LDS pointer = DS addr)
    const unsigned aA = (unsigned)(uintptr_t)(ldsA + wr * 8192 + lane * 16);
    const unsigned aB = (unsigned)(uintptr_t)(ldsB + wc * 4096 + lane * 16);

    i32x16 acc[4][2] = {};
    i32x4 fA[2][2][4];                // [set][khalf][rsub] — all indices static
    i32x4 fB[2][2][2];                // [set][khalf][csub]

    // ---- prologue: stage tile0->slot0, tile1->slot1; land tile0; read set0 ----
    STAGE(0)
    STAGE(1)
    asm volatile("s_waitcnt vmcnt(4)" ::: "memory");   // tile0 landed
    __builtin_amdgcn_s_barrier();
    READ12(0, 0)

    // ---- main loop: t = 0..59 in 15 groups of 4 ----
    // tile t: stage slot (t+2)%4, read slot (t+1)%4 into set (t+1)%2, MFMA set t%2
    for (int i = 0; i < 15; ++i) {
        TILE_FULL(2, 16384, 1, 0)     // t%4==0
        TILE_FULL(3, 32768, 0, 1)     // t%4==1
        TILE_FULL(0, 49152, 1, 0)     // t%4==2
        TILE_FULL(1,     0, 0, 1)     // t%4==3
    }
    // ---- t=60 (stage tile62->slot2), t=61 (stage tile63->slot3) ----
    TILE_FULL(2, 16384, 1, 0)
    TILE_FULL(3, 32768, 0, 1)
    // ---- t=62: no stage; drain all staging; read slot3; MFMA set0 ----
    {
        asm volatile("s_waitcnt vmcnt(0)" ::: "memory");
        __builtin_amdgcn_s_barrier();
        READ12(1, 49152)
        asm volatile("s_waitcnt lgkmcnt(12)" ::: "memory");
        __builtin_amdgcn_sched_barrier(0);
        __builtin_amdgcn_s_setprio(1);
        MFMA_HALF(0, 0)
        MFMA_HALF(0, 1)
        __builtin_amdgcn_s_setprio(0);
    }
    // ---- t=63: final MFMA (set1); wait its reads first ----
    asm volatile("s_waitcnt lgkmcnt(0)" ::: "memory");
    __builtin_amdgcn_sched_barrier(0);
    MFMA_HALF(1, 0)
    MFMA_HALF(1, 1)

    // ---- epilogue: out = clip(round((acc + bias) * (is*ws/os) + zp)) as int32 ----
    // 32x32 C/D layout (HW-verified): col = lane&31, row = (reg&3) + 8*(reg>>2) + 4*(lane>>5)
    const float is_v = iscale[0];
    const float os_v = oscale[0];
    const float zpf = (float)zp[0];
    #pragma unroll
    for (int c = 0; c < 2; c++) {
        int col = bcol + wc * 64 + c * 32 + (lane & 31);
        float sf = (is_v * wscale[col]) / os_v;
        int bz = bias[col];
        #pragma unroll
        for (int r = 0; r < 4; r++) {
            int rowb = brow + wr * 128 + r * 32 + 4 * (lane >> 5);
            #pragma unroll
            for (int reg = 0; reg < 16; reg++) {
                int row = rowb + (reg & 3) + 8 * (reg >> 2);
                float v = (float)(acc[r][c][reg] + bz) * sf + zpf;
                v = rintf(v);
                v = fminf(fmaxf(v, -128.0f), 127.0f);
                out[(size_t)row * N_DIM + col] = (int)v;
            }
        }
    }
}

#define MFMA_I8(a, b, c) __builtin_amdgcn_mfma_i32_16x16x64_i8((a), (b), (c), 0, 0, 0)

// Fallback (no workspace): direct int32 consumption, 128^2 tile (round-2 proven).
__global__ void qgemm_fallback(const int* __restrict__ x32, const int* __restrict__ w32,
                               const int* __restrict__ bias, const float* __restrict__ wscale,
                               const float* __restrict__ iscale, const float* __restrict__ oscale,
                               const int* __restrict__ zp, int* __restrict__ out) {
    __shared__ int8_t As[128][64];
    __shared__ int8_t Bs[128][64];
    const int tid  = threadIdx.x;
    const int wave = tid >> 6;
    const int lane = tid & 63;
    int b = blockIdx.x;
    int s = (b & 7) * (gridDim.x >> 3) + (b >> 3);
    const int bcol = (s & 31) * 128;
    const int brow = (s >> 5) * 128;
    const int wr = wave >> 1;
    const int wc = wave & 1;
    i32x4 acc[4][4] = {};
    for (int kt = 0; kt < K_DIM; kt += 64) {
        int row = tid >> 1;
        int h = tid & 1;
        const i32x4* sa = (const i32x4*)(x32 + (size_t)(brow + row) * K_DIM + kt + h * 32);
        const i32x4* sb = (const i32x4*)(w32 + (size_t)(bcol + row) * K_DIM + kt + h * 32);
        int pa[8], pb[8];
        #pragma unroll
        for (int j = 0; j < 8; j++) { pa[j] = pack4(sa[j]); pb[j] = pack4(sb[j]); }
        *(i32x4*)&As[row][h * 32]      = *(i32x4*)&pa[0];
        *(i32x4*)&As[row][h * 32 + 16] = *(i32x4*)&pa[4];
        *(i32x4*)&Bs[row][h * 32]      = *(i32x4*)&pb[0];
        *(i32x4*)&Bs[row][h * 32 + 16] = *(i32x4*)&pb[4];
        __syncthreads();
        i32x4 a_frag[4], b_frag[4];
        #pragma unroll
        for (int m = 0; m < 4; m++)
            a_frag[m] = *(const i32x4*)&As[wr * 64 + m * 16 + (lane & 15)][(lane >> 4) * 16];
        #pragma unroll
        for (int n = 0; n < 4; n++)
            b_frag[n] = *(const i32x4*)&Bs[wc * 64 + n * 16 + (lane & 15)][(lane >> 4) * 16];
        #pragma unroll
        for (int m = 0; m < 4; m++)
            #pragma unroll
            for (int n = 0; n < 4; n++)
                acc[m][n] = MFMA_I8(a_frag[m], b_frag[n], acc[m][n]);
        __syncthreads();
    }
    const float is_v = iscale[0];
    const float os_v = oscale[0];
    const float zpf = (float)zp[0];
    #pragma unroll
    for (int n = 0; n < 4; n++) {
        int col = bcol + wc * 64 + n * 16 + (lane & 15);
        float sf = (is_v * wscale[col]) / os_v;
        int bz = bias[col];
        #pragma unroll
        for (int m = 0; m < 4; m++) {
            int row0 = brow + wr * 64 + m * 16 + (lane >> 4) * 4;
            #pragma unroll
            for (int r = 0; r < 4; r++) {
                float v = (float)(acc[m][n][r] + bz) * sf + zpf;
                v = rintf(v);
                v = fminf(fmaxf(v, -128.0f), 127.0f);
                out[(size_t)(row0 + r) * N_DIM + col] = (int)v;
            }
        }
    }
}

extern "C" void kernel_launch(void* const* d_in, const int* in_sizes, int n_in,
                              void* d_out, int out_size, void* d_ws, size_t ws_size,
                              hipStream_t stream) {
    const int*   x32    = (const int*)d_in[0];
    const int*   w32    = (const int*)d_in[1];
    const int*   bias   = (const int*)d_in[2];
    const float* wscale = (const float*)d_in[3];
    const float* iscale = (const float*)d_in[4];
    const float* oscale = (const float*)d_in[5];
    const int*   zp     = (const int*)d_in[6];
    int* out = (int*)d_out;

    const size_t need = (size_t)M_DIM * K_DIM + (size_t)N_DIM * K_DIM;  // 50.3 MB
    const size_t lds_bytes = 4 * (size_t)(ABUF + BBUF);                 // 131072

    if (ws_size >= need) {
        int8_t* xp = (int8_t*)d_ws;
        int8_t* wp = xp + (size_t)M_DIM * K_DIM;
        const int nblkA = (M_DIM / 32) * NKT2;   // 32768
        const int nblkB = (N_DIM / 32) * NKT2;   // 16384
        pack_panels32_kernel<<<nblkA / 4, 256, 0, stream>>>(x32, xp, nblkA);
        pack_panels32_kernel<<<nblkB / 4, 256, 0, stream>>>(w32, wp, nblkB);
        (void)hipFuncSetAttribute((const void*)qgemm32_kernel,
                                  hipFuncAttributeMaxDynamicSharedMemorySize,
                                  (int)lds_bytes);
        qgemm32_kernel<<<NBLK, 512, lds_bytes, stream>>>(xp, wp, bias, wscale, iscale, oscale, zp, out);
    } else {
        qgemm_fallback<<<2048, 256, 0, stream>>>(x32, w32, bias, wscale, iscale, oscale, zp, out);
    }
}